// Round 4
// baseline (1340.095 us; speedup 1.0000x reference)
//
#include <hip/hip_runtime.h>
#include <hip/hip_bf16.h>

#define NN 100000
#define NE 1600000
#define BN_EPS 1e-5f
#define NB 391                                      // ceil(NN/256) for scan
#define NBKT 782                                    // ceil(NN/128) dst buckets
#define BCAP 512                                    // per (region,bucket) capacity; mean 256

typedef __attribute__((ext_vector_type(8))) short bf16x8;
typedef __attribute__((ext_vector_type(4))) float f32x4;
typedef __attribute__((ext_vector_type(2))) float f32x2;

static __device__ __forceinline__ ushort f2b(float f) {
  __hip_bfloat16 h = __float2bfloat16(f);            // RNE
  return __builtin_bit_cast(ushort, h);
}
static __device__ __forceinline__ float blo(uint v) { return __builtin_bit_cast(float, v << 16); }
static __device__ __forceinline__ float bhi(uint v) { return __builtin_bit_cast(float, v & 0xFFFF0000u); }

// ---------------- CSR build, pass A: degree count + region-binned edges ----------------
// region = blockIdx&7 ~= XCD (round-robin dispatch) -> sequential slots in a region are
// written by one XCD's L2 -> full-line merges instead of 64B/edge partial writebacks.
__global__ __launch_bounds__(256) void k_bin(const int* __restrict__ ei, int* __restrict__ deg,
                                             int* __restrict__ bfill, uint* __restrict__ binned) {
  const int e = blockIdx.x * 256 + threadIdx.x;      // grid covers NE exactly
  const int s = ei[e];
  const int d = ei[NE + e];
  atomicAdd(&deg[d], 1);
  const int bucket = d >> 7;
  const int idx = (blockIdx.x & 7) * NBKT + bucket;
  const int pos = atomicAdd(&bfill[idx], 1);
  binned[(size_t)idx * BCAP + pos] = ((uint)(d & 127) << 17) | (uint)s;
}

__global__ __launch_bounds__(256) void k_dinv(const int* __restrict__ deg, float* __restrict__ dinv) {
  int v = blockIdx.x * 256 + threadIdx.x;
  if (v < NN) dinv[v] = rsqrtf((float)deg[v] + 1.0f);
}

// level 1: per-block sums of deg
__global__ __launch_bounds__(256) void k_scan1(const int* __restrict__ deg, int* __restrict__ bsum) {
  __shared__ int lds[256];
  const int t = threadIdx.x;
  const int i = blockIdx.x * 256 + t;
  lds[t] = (i < NN) ? deg[i] : 0;
  __syncthreads();
  for (int d = 128; d > 0; d >>= 1) {
    if (t < d) lds[t] += lds[t + d];
    __syncthreads();
  }
  if (t == 0) bsum[blockIdx.x] = lds[0];
}

// level 2: scan the NB block sums
__global__ __launch_bounds__(512) void k_scan2(const int* __restrict__ bsum, int* __restrict__ boff,
                                               int* __restrict__ rp) {
  __shared__ int lds[512];
  const int t = threadIdx.x;
  const int own = (t < NB) ? bsum[t] : 0;
  lds[t] = own;
  __syncthreads();
  for (int d = 1; d < 512; d <<= 1) {
    int v = (t >= d) ? lds[t - d] : 0;
    __syncthreads();
    lds[t] += v;
    __syncthreads();
  }
  if (t < NB) boff[t] = lds[t] - own;
  if (t == 511) rp[NN] = lds[511];
}

// level 3: in-block exclusive scan + block offset
__global__ __launch_bounds__(256) void k_scan3(const int* __restrict__ deg, const int* __restrict__ boff,
                                               int* __restrict__ rp) {
  __shared__ int lds[256];
  const int t = threadIdx.x;
  const int i = blockIdx.x * 256 + t;
  const int own = (i < NN) ? deg[i] : 0;
  lds[t] = own;
  __syncthreads();
  for (int d = 1; d < 256; d <<= 1) {
    int v = (t >= d) ? lds[t - d] : 0;
    __syncthreads();
    lds[t] += v;
    __syncthreads();
  }
  if (i < NN) rp[i] = boff[blockIdx.x] + lds[t] - own;
}

// ---------------- CSR build, pass B: per-bucket fine scatter (one block/bucket) ----------------
__global__ __launch_bounds__(256) void k_scatter2(const uint* __restrict__ binned,
                                                  const int* __restrict__ bfill,
                                                  const int* __restrict__ rp, int* __restrict__ csr) {
  __shared__ int lfill[128];
  __shared__ int lrp[128];
  const int t = threadIdx.x;
  const int bucket = blockIdx.x;
  const int v0 = bucket << 7;
  if (t < 128) {
    lfill[t] = 0;
    lrp[t] = (v0 + t < NN) ? rp[v0 + t] : 0;
  }
  __syncthreads();
  #pragma unroll
  for (int r = 0; r < 8; ++r) {
    const int idx = r * NBKT + bucket;
    const int c = bfill[idx];
    const uint* seg = binned + (size_t)idx * BCAP;
    for (int j = t; j < c; j += 256) {
      const uint u = seg[j];
      const int ld = u >> 17;
      const int s = (int)(u & 0x1FFFFu);
      const int pos = lrp[ld] + atomicAdd(&lfill[ld], 1);
      csr[pos] = s;
    }
  }
}

// ---------------- W prep: wt[layer][n][k] = bf16(W[k][n]) ----------------
__global__ __launch_bounds__(128) void k_wt(const float* __restrict__ W0, const float* __restrict__ W1,
                                            const float* __restrict__ W2, ushort* __restrict__ wt) {
  const int lay = blockIdx.y, n = blockIdx.x, k = threadIdx.x;
  const float* W = (lay == 0) ? W0 : (lay == 1) ? W1 : W2;
  wt[lay * 16384 + n * 128 + k] = f2b(W[k * 128 + n]);
}

// ---------------- x -> bf16 ----------------
__global__ __launch_bounds__(256) void k_tobf(const float* __restrict__ x, ushort* __restrict__ o) {
  int i = blockIdx.x * 256 + threadIdx.x;
  float4 v = ((const float4*)x)[i];
  ushort4 u;
  u.x = f2b(v.x); u.y = f2b(v.y); u.z = f2b(v.z); u.w = f2b(v.w);
  ((ushort4*)o)[i] = u;
}

// ---------------- GEMM (MFMA bf16): hw = h @ W ----------------
__global__ __launch_bounds__(256) void k_gemm(const ushort* __restrict__ h,
                                              const ushort* __restrict__ wt,   // [n][k] bf16
                                              ushort* __restrict__ hw) {
  __shared__ ushort wlds[128 * 128];
  const int t = threadIdx.x;
  {
    const uint4* src = (const uint4*)wt;
    uint4* dst = (uint4*)wlds;
    #pragma unroll
    for (int i = 0; i < 8; ++i) {
      int idx = t + i * 256;
      int n = idx >> 4;
      dst[idx ^ (n & 7)] = src[idx];
    }
  }
  __syncthreads();

  const int wv = t >> 6, l = t & 63;
  const int lr = l & 15, lk = l >> 4;
  const int row0 = blockIdx.x * 128 + wv * 32;
  f32x4 acc[2][8] = {};
  const uint4* wchunks = (const uint4*)wlds;

  #pragma unroll
  for (int kb = 0; kb < 4; ++kb) {
    const int r0 = min(row0 + lr, NN - 1);
    const int r1 = min(row0 + 16 + lr, NN - 1);
    const bf16x8 a0 = *(const bf16x8*)(h + (size_t)r0 * 128 + kb * 32 + lk * 8);
    const bf16x8 a1 = *(const bf16x8*)(h + (size_t)r1 * 128 + kb * 32 + lk * 8);
    #pragma unroll
    for (int nt = 0; nt < 8; ++nt) {
      const int n = nt * 16 + lr;
      const int chunk = n * 16 + ((kb * 4 + lk) ^ (n & 7));
      const bf16x8 b = *(const bf16x8*)(wchunks + chunk);
      acc[0][nt] = __builtin_amdgcn_mfma_f32_16x16x32_bf16(a0, b, acc[0][nt], 0, 0, 0);
      acc[1][nt] = __builtin_amdgcn_mfma_f32_16x16x32_bf16(a1, b, acc[1][nt], 0, 0, 0);
    }
  }
  #pragma unroll
  for (int rt = 0; rt < 2; ++rt)
    #pragma unroll
    for (int j = 0; j < 4; ++j) {
      const int row = row0 + rt * 16 + lk * 4 + j;
      if (row < NN) {
        #pragma unroll
        for (int nt = 0; nt < 8; ++nt)
          hw[(size_t)row * 128 + nt * 16 + lr] = f2b(acc[rt][nt][j]);
      }
    }
}

// ---------------- aggregation: XCD-sliced gather ----------------
// slice = blockIdx&7 ~= XCD; each XCD gathers only its 16-feature column slice of hw
// (3.2 MB, L2-resident). 8-lane groups per node; csr/dinv via width-8 shfl broadcast.
__global__ __launch_bounds__(256) void k_agg(const ushort* __restrict__ hw,
                                             const int* __restrict__ rp, const int* __restrict__ csr,
                                             const float* __restrict__ dinv, const float* __restrict__ bias,
                                             float* __restrict__ out) {
  const int slice = blockIdx.x & 7;
  const int ng = blockIdx.x >> 3;
  const int g = threadIdx.x >> 3;                    // node slot 0..31
  const int sub = threadIdx.x & 7;
  const int v = ng * 32 + g;                         // grid covers NN exactly (3125*32)
  const int beg = rp[v], end = rp[v + 1];
  const size_t coff = (size_t)slice * 16 + sub * 2;  // ushort offset within row
  float ax = 0.f, ay = 0.f;
  int i = beg;
  for (; i + 8 <= end; i += 8) {
    const int e = __builtin_nontemporal_load(csr + i + sub);
    const float dn = dinv[e];
    #pragma unroll
    for (int j = 0; j < 8; ++j) {
      const int s = __shfl(e, j, 8);
      const float dj = __shfl(dn, j, 8);
      const uint vv = *(const uint*)(hw + (size_t)s * 128 + coff);
      ax = fmaf(dj, blo(vv), ax);
      ay = fmaf(dj, bhi(vv), ay);
    }
  }
  for (; i < end; ++i) {
    const int s = __builtin_nontemporal_load(csr + i);
    const float ds = dinv[s];
    const uint vv = *(const uint*)(hw + (size_t)s * 128 + coff);
    ax = fmaf(ds, blo(vv), ax);
    ay = fmaf(ds, bhi(vv), ay);
  }
  const float dv = dinv[v];
  const uint sv = *(const uint*)(hw + (size_t)v * 128 + coff);
  const f32x2 bb = *(const f32x2*)(bias + slice * 16 + sub * 2);
  f32x2 o;
  o.x = fmaf(ax, dv, fmaf(blo(sv), dv * dv, bb.x));
  o.y = fmaf(ay, dv, fmaf(bhi(sv), dv * dv, bb.y));
  __builtin_nontemporal_store(o, (f32x2*)(out + (size_t)v * 128 + slice * 16 + sub * 2));
}

// ---------------- BatchNorm ----------------
__global__ __launch_bounds__(256) void k_bnstats(const float* __restrict__ h, float* __restrict__ stats) {
  __shared__ float rs[256], rs2[256];
  const int t = threadIdx.x;
  const int col = t & 127, rg = t >> 7;
  const int row0 = blockIdx.x * 128;
  const int rend = min(row0 + 128, NN);
  float s = 0.f, s2 = 0.f;
  for (int r = row0 + rg; r < rend; r += 2) {
    float v = h[(size_t)r * 128 + col];
    s += v;
    s2 = fmaf(v, v, s2);
  }
  rs[t] = s; rs2[t] = s2;
  __syncthreads();
  if (t < 128) {
    atomicAdd(&stats[t], rs[t] + rs[t + 128]);
    atomicAdd(&stats[128 + t], rs2[t] + rs2[t + 128]);
  }
}

__global__ void k_bnfin(const float* __restrict__ stats, const float* __restrict__ gamma,
                        const float* __restrict__ beta, float* __restrict__ sc, float* __restrict__ sh) {
  const int c = threadIdx.x;
  const float inv_n = 1.0f / (float)NN;
  const float mean = stats[c] * inv_n;
  const float var = fmaxf(stats[128 + c] * inv_n - mean * mean, 0.f);
  const float k = gamma[c] * rsqrtf(var + BN_EPS);
  sc[c] = k;
  sh[c] = fmaf(-mean, k, beta[c]);
}

__global__ __launch_bounds__(256) void k_bnrelu(const float* __restrict__ h, ushort* __restrict__ ob,
                                                float* __restrict__ of, const int write_f32,
                                                const float* __restrict__ sc, const float* __restrict__ sh) {
  const int i = blockIdx.x * 256 + threadIdx.x;
  const int c = (i & 31) * 4;
  float4 v = ((const float4*)h)[i];
  v.x = fmaxf(fmaf(sc[c + 0], v.x, sh[c + 0]), 0.f);
  v.y = fmaxf(fmaf(sc[c + 1], v.y, sh[c + 1]), 0.f);
  v.z = fmaxf(fmaf(sc[c + 2], v.z, sh[c + 2]), 0.f);
  v.w = fmaxf(fmaf(sc[c + 3], v.w, sh[c + 3]), 0.f);
  ushort4 u;
  u.x = f2b(v.x); u.y = f2b(v.y); u.z = f2b(v.z); u.w = f2b(v.w);
  ((ushort4*)ob)[i] = u;
  if (write_f32) ((float4*)of)[i] = v;
}

// ---------------- launch ----------------
extern "C" void kernel_launch(void* const* d_in, const int* in_sizes, int n_in,
                              void* d_out, int out_size, void* d_ws, size_t ws_size,
                              hipStream_t stream) {
  const float* x  = (const float*)d_in[0];
  const int*   ei = (const int*)d_in[1];
  const float* W[3]  = {(const float*)d_in[2],  (const float*)d_in[6],  (const float*)d_in[10]};
  const float* b[3]  = {(const float*)d_in[3],  (const float*)d_in[7],  (const float*)d_in[11]};
  const float* g[3]  = {(const float*)d_in[4],  (const float*)d_in[8],  (const float*)d_in[12]};
  const float* be[3] = {(const float*)d_in[5],  (const float*)d_in[9],  (const float*)d_in[13]};

  char* ws = (char*)d_ws;
  ushort* hwb   = (ushort*)(ws);                // NN*128 bf16 = 25,600,000 B
  // binned/bfill overlay hwb: dead once k_scatter2 completes, before first k_gemm
  uint*   binned = (uint*)(ws);                 // 8*NBKT*BCAP*4 = 12,812,288 B
  int*    bfill  = (int*)(ws + 13000000);       // 8*NBKT*4 = 25,024 B
  ushort* hin   = (ushort*)(ws + 25600000);     // NN*128 bf16 (layer input)
  int*    csr   = (int*)(ws + 51200000);        // NE ints
  int*    deg   = (int*)(ws + 57600000);
  int*    rp    = (int*)(ws + 58000000);
  float*  dinv  = (float*)(ws + 58400016);
  ushort* wtb   = (ushort*)(ws + 58800016);     // 3 x 128x128 bf16 (W^T)
  float*  stats = (float*)(ws + 58898320);
  float*  sc    = (float*)(ws + 58899344);
  float*  sh    = (float*)(ws + 58899856);
  int*    bsum  = (int*)(ws + 58900368);        // NB ints
  int*    boff  = (int*)(ws + 58901936);        // NB ints
  float*  hbuf  = (float*)d_out;                // fp32 agg/BN buffer (also final output)

  hipMemsetAsync(deg, 0, NN * 4, stream);
  hipMemsetAsync(bfill, 0, 8 * NBKT * 4, stream);
  k_bin<<<NE / 256, 256, 0, stream>>>(ei, deg, bfill, binned);
  k_dinv<<<(NN + 255) / 256, 256, 0, stream>>>(deg, dinv);
  k_scan1<<<NB, 256, 0, stream>>>(deg, bsum);
  k_scan2<<<1, 512, 0, stream>>>(bsum, boff, rp);
  k_scan3<<<NB, 256, 0, stream>>>(deg, boff, rp);
  k_scatter2<<<NBKT, 256, 0, stream>>>(binned, bfill, rp, csr);
  k_wt<<<dim3(128, 3), 128, 0, stream>>>(W[0], W[1], W[2], wtb);
  k_tobf<<<NN * 128 / 1024, 256, 0, stream>>>(x, hin);

  for (int L = 0; L < 3; ++L) {
    k_gemm<<<(NN + 127) / 128, 256, 0, stream>>>(hin, wtb + L * 16384, hwb);
    k_agg<<<25000, 256, 0, stream>>>(hwb, rp, csr, dinv, b[L], hbuf);
    hipMemsetAsync(stats, 0, 256 * 4, stream);
    k_bnstats<<<(NN + 127) / 128, 256, 0, stream>>>(hbuf, stats);
    k_bnfin<<<1, 128, 0, stream>>>(stats, g[L], be[L], sc, sh);
    k_bnrelu<<<NN * 128 / 1024, 256, 0, stream>>>(hbuf, hin, hbuf, (L == 2) ? 1 : 0, sc, sh);
  }
}